// Round 3
// baseline (433.568 us; speedup 1.0000x reference)
//
#include <hip/hip_runtime.h>

#define NN 50000
#define NE 800000
#define DIM 128
#define NEG_SLOPE 0.1f

// ---------- preprocessing: CSR-by-dst build ----------

__global__ void k_init(float* __restrict__ deg, int* __restrict__ hist) {
    int i = blockIdx.x * 256 + threadIdx.x;
    if (i < NN) { deg[i] = 1.0f; hist[i] = 0; }   // self-loop weight 1
}

__global__ void k_deg_hist(const int* __restrict__ ei, const float* __restrict__ attr,
                           const int* __restrict__ etype, const float* __restrict__ scale,
                           float* __restrict__ deg, int* __restrict__ hist) {
    int e = blockIdx.x * 256 + threadIdx.x;
    if (e >= NE) return;
    float w = scale[etype[e]] * attr[e];
    int d = ei[NE + e];
    atomicAdd(&deg[d], w);
    atomicAdd(&hist[d], 1);
}

// scan1: per-block (1024 elems) exclusive scan -> rowptr, block sums -> aux.
// Also converts deg -> dinv in place (fused, saves a launch).
__global__ void k_scan1(const int* __restrict__ hist, int* __restrict__ rowptr,
                        int* __restrict__ aux, float* __restrict__ deg) {
    __shared__ int sdata[256];
    int t = threadIdx.x;
    int base = blockIdx.x * 1024 + t * 4;
    int v[4]; int s = 0;
    #pragma unroll
    for (int j = 0; j < 4; ++j) { v[j] = (base + j < NN) ? hist[base + j] : 0; s += v[j]; }
    #pragma unroll
    for (int j = 0; j < 4; ++j) {
        if (base + j < NN) {
            float d = deg[base + j];
            deg[base + j] = d > 0.0f ? (1.0f / sqrtf(d)) : 0.0f;
        }
    }
    sdata[t] = s;
    __syncthreads();
    for (int off = 1; off < 256; off <<= 1) {
        int x = (t >= off) ? sdata[t - off] : 0;
        __syncthreads();
        sdata[t] += x;
        __syncthreads();
    }
    int run = sdata[t] - s;  // exclusive prefix of this thread's chunk
    if (t == 255) aux[blockIdx.x] = sdata[255];
    #pragma unroll
    for (int j = 0; j < 4; ++j) { if (base + j < NN) rowptr[base + j] = run; run += v[j]; }
}

// scan2: exclusive scan of 49 block sums (one wave)
__global__ void k_scan2(int* __restrict__ aux) {
    int t = threadIdx.x;
    int v = (t < 49) ? aux[t] : 0;
    int orig = v;
    for (int off = 1; off < 64; off <<= 1) {
        int y = __shfl_up(v, off, 64);
        if (t >= off) v += y;
    }
    if (t < 49) aux[t] = v - orig;
}

// scan3: add block offsets; init cursor (hist) = rowptr; set rowptr[NN]=NE
__global__ void k_scan3(int* __restrict__ rowptr, int* __restrict__ hist,
                        const int* __restrict__ aux) {
    int i = blockIdx.x * 256 + threadIdx.x;
    if (i < NN) {
        int v = rowptr[i] + aux[i >> 10];
        rowptr[i] = v;
        hist[i] = v;
    }
    if (i == 0) rowptr[NN] = NE;
}

// place edges into CSR order; compute normalized coefficient on the fly
__global__ void k_place(const int* __restrict__ ei, const float* __restrict__ attr,
                        const int* __restrict__ etype, const float* __restrict__ scale,
                        const float* __restrict__ dinv, int* __restrict__ cursor,
                        int* __restrict__ srcs, float* __restrict__ coefs) {
    int e = blockIdx.x * 256 + threadIdx.x;
    if (e >= NE) return;
    int s = ei[e], d = ei[NE + e];
    float w = scale[etype[e]] * attr[e];
    float nrm = dinv[s] * w * dinv[d];
    int pos = atomicAdd(&cursor[d], 1);
    srcs[pos] = s;
    coefs[pos] = nrm;
}

// ---------- fused layer: out = leaky?( (agg(xin) + dinv^2 xin) @ W + b ) ----------
// Block = 256 threads = 4 waves; 16 dst rows per block (NN = 3125 * 16, exact).
// Phase 1: wave w aggregates rows w*4..w*4+3; lane owns 2 cols; 8-deep gather unroll.
// Phase 2: 16x128 @ 128x128 register-blocked GEMM from LDS (acc[2][4]/thread).
template<bool LEAKY>
__global__ __launch_bounds__(256)
void k_layer(const float* __restrict__ xin, const float* __restrict__ coefs,
             const int* __restrict__ srcs, const int* __restrict__ rowptr,
             const float* __restrict__ dinv, const float* __restrict__ W,
             const float* __restrict__ b, float* __restrict__ out) {
    __shared__ float Xs[16][132];
    int tid = threadIdx.x;
    int row0 = blockIdx.x * 16;
    int wv = tid >> 6;
    int lane = tid & 63;

    // phase 1: aggregate (no row guards: grid covers NN exactly)
    for (int rr = 0; rr < 4; ++rr) {
        int row = row0 + wv * 4 + rr;
        float di = dinv[row];
        float2 sv = *(const float2*)&xin[row * DIM + lane * 2];
        float ax = di * di * sv.x;
        float ay = di * di * sv.y;
        int p = rowptr[row], p1 = rowptr[row + 1];
        for (; p + 8 <= p1; p += 8) {
            int   s[8]; float c[8]; float2 v[8];
            #pragma unroll
            for (int j = 0; j < 8; ++j) { s[j] = srcs[p + j]; c[j] = coefs[p + j]; }
            #pragma unroll
            for (int j = 0; j < 8; ++j) v[j] = *(const float2*)&xin[s[j] * DIM + lane * 2];
            #pragma unroll
            for (int j = 0; j < 8; ++j) { ax = fmaf(c[j], v[j].x, ax); ay = fmaf(c[j], v[j].y, ay); }
        }
        if (p + 4 <= p1) {
            int   s[4]; float c[4]; float2 v[4];
            #pragma unroll
            for (int j = 0; j < 4; ++j) { s[j] = srcs[p + j]; c[j] = coefs[p + j]; }
            #pragma unroll
            for (int j = 0; j < 4; ++j) v[j] = *(const float2*)&xin[s[j] * DIM + lane * 2];
            #pragma unroll
            for (int j = 0; j < 4; ++j) { ax = fmaf(c[j], v[j].x, ax); ay = fmaf(c[j], v[j].y, ay); }
            p += 4;
        }
        for (; p < p1; ++p) {
            float c = coefs[p];
            float2 v = *(const float2*)&xin[srcs[p] * DIM + lane * 2];
            ax = fmaf(c, v.x, ax);
            ay = fmaf(c, v.y, ay);
        }
        float2 res; res.x = ax; res.y = ay;
        *(float2*)&Xs[wv * 4 + rr][lane * 2] = res;
    }
    __syncthreads();

    // phase 2: GEMM 16x128
    int tx = tid & 31, ty = tid >> 5;       // tx: 4-col group, ty: 2-row group (0..7)
    float acc[2][4] = {};
    for (int k = 0; k < DIM; k += 4) {
        float4 xv[2];
        #pragma unroll
        for (int r = 0; r < 2; ++r) xv[r] = *(const float4*)&Xs[ty * 2 + r][k];
        #pragma unroll
        for (int kk = 0; kk < 4; ++kk) {
            float4 wv2 = *(const float4*)&W[(k + kk) * DIM + tx * 4];
            #pragma unroll
            for (int r = 0; r < 2; ++r) {
                float xs = (&xv[r].x)[kk];
                acc[r][0] = fmaf(xs, wv2.x, acc[r][0]);
                acc[r][1] = fmaf(xs, wv2.y, acc[r][1]);
                acc[r][2] = fmaf(xs, wv2.z, acc[r][2]);
                acc[r][3] = fmaf(xs, wv2.w, acc[r][3]);
            }
        }
    }

    float4 bv = *(const float4*)&b[tx * 4];
    #pragma unroll
    for (int r = 0; r < 2; ++r) {
        int row = row0 + ty * 2 + r;
        float4 v;
        v.x = acc[r][0] + bv.x; v.y = acc[r][1] + bv.y;
        v.z = acc[r][2] + bv.z; v.w = acc[r][3] + bv.w;
        if (LEAKY) {
            v.x = v.x > 0.f ? v.x : NEG_SLOPE * v.x;
            v.y = v.y > 0.f ? v.y : NEG_SLOPE * v.y;
            v.z = v.z > 0.f ? v.z : NEG_SLOPE * v.z;
            v.w = v.w > 0.f ? v.w : NEG_SLOPE * v.w;
        }
        *(float4*)&out[row * DIM + tx * 4] = v;
    }
}

extern "C" void kernel_launch(void* const* d_in, const int* in_sizes, int n_in,
                              void* d_out, int out_size, void* d_ws, size_t ws_size,
                              hipStream_t stream) {
    const float* x     = (const float*)d_in[0];
    const int*   ei    = (const int*)d_in[1];
    const float* attr  = (const float*)d_in[2];
    const int*   etype = (const int*)d_in[3];
    const float* scale = (const float*)d_in[4];
    const float* W1 = (const float*)d_in[5];
    const float* b1 = (const float*)d_in[6];
    const float* W2 = (const float*)d_in[7];
    const float* b2 = (const float*)d_in[8];
    const float* W3 = (const float*)d_in[9];
    const float* b3 = (const float*)d_in[10];
    float* out = (float*)d_out;

    // ws layout:
    float* B2     = (float*)d_ws;              // NN*DIM
    float* coefs  = B2 + NN * DIM;             // NE
    float* dinv   = coefs + NE;                // NN (deg -> dinv in place)
    int*   srcs   = (int*)(dinv + NN);         // NE
    int*   hist   = srcs + NE;                 // NN (hist -> cursor)
    int*   rowptr = hist + NN;                 // NN+1
    int*   aux    = rowptr + NN + 1;           // 64

    const int nb_n = (NN + 255) / 256;         // 196
    const int nb_e = NE / 256;                 // 3125
    const int nb_l = NN / 16;                  // 3125 (exact)
    const int nb_s1 = (NN + 1023) / 1024;      // 49

    k_init<<<nb_n, 256, 0, stream>>>(dinv, hist);
    k_deg_hist<<<nb_e, 256, 0, stream>>>(ei, attr, etype, scale, dinv, hist);
    k_scan1<<<nb_s1, 256, 0, stream>>>(hist, rowptr, aux, dinv);
    k_scan2<<<1, 64, 0, stream>>>(aux);
    k_scan3<<<nb_n, 256, 0, stream>>>(rowptr, hist, aux);
    k_place<<<nb_e, 256, 0, stream>>>(ei, attr, etype, scale, dinv, hist, srcs, coefs);

    // layer 1: x -> d_out ; layer 2: d_out -> B2 ; layer 3: B2 -> d_out
    k_layer<true ><<<nb_l, 256, 0, stream>>>(x,   coefs, srcs, rowptr, dinv, W1, b1, out);
    k_layer<true ><<<nb_l, 256, 0, stream>>>(out, coefs, srcs, rowptr, dinv, W2, b2, B2);
    k_layer<false><<<nb_l, 256, 0, stream>>>(B2,  coefs, srcs, rowptr, dinv, W3, b3, out);
}